// Round 1
// baseline (150.352 us; speedup 1.0000x reference)
//
#include <hip/hip_runtime.h>
#include <stdint.h>

// Problem constants: z (32,384,28,28) fp32; codebook (2048,384) fp32.
// N tokens = 32*784 = 25088, D = 384, K = 2048. out = z_q (9633792 f32) + loss (1 f32).
#define M_TOK 25088
#define D_DIM 384
#define K_CB  2048
#define BM    128
#define BN    256
#define BKS   64
#define NCHUNK (K_CB / BN)   // 8
#define KSTEPS (D_DIM / BKS) // 6
#define OUT_ELEMS 9633792

typedef __attribute__((ext_vector_type(8))) short short8;
typedef __attribute__((ext_vector_type(4))) float f32x4;

static __device__ __forceinline__ unsigned short f2bf(float f) {
    uint32_t u = __float_as_uint(f);
    u += 0x7FFF + ((u >> 16) & 1);   // RNE
    return (unsigned short)(u >> 16);
}

static __device__ __forceinline__ void gl_lds16(const void* g, void* l) {
    __builtin_amdgcn_global_load_lds((const __attribute__((address_space(1))) void*)g,
                                     (__attribute__((address_space(3))) void*)l,
                                     16, 0, 0);
}

// ---------------- codebook prep: fp32 -> bf16 + row norms ----------------
__global__ __launch_bounds__(256) void prep_cb_kernel(
    const float* __restrict__ cb, unsigned short* __restrict__ cb16,
    float* __restrict__ cnorm) {
    int t = threadIdx.x;
    int lane = t & 63, wv = t >> 6;
    int row = blockIdx.x * 4 + wv;               // grid 512 -> 2048 rows
    const float* src = cb + (size_t)row * D_DIM;
    unsigned short* dst = cb16 + (size_t)row * D_DIM;
    float ss = 0.f;
#pragma unroll
    for (int i = 0; i < 6; ++i) {
        float v = src[lane + i * 64];
        dst[lane + i * 64] = f2bf(v);
        ss += v * v;
    }
#pragma unroll
    for (int d = 32; d; d >>= 1) ss += __shfl_xor(ss, d);
    if (lane == 0) cnorm[row] = ss;
}

// ---------------- z transpose: (b,c,s) fp32 -> (token, c) bf16 ----------------
// 64c x 64s tiles through LDS with XOR swizzle on the c index (bits 3..5 ^ s&7).
__global__ __launch_bounds__(256) void transpose_z_kernel(
    const float* __restrict__ z, unsigned short* __restrict__ zf) {
    __shared__ unsigned short tile[64 * 64];
    int bid = blockIdx.x;                 // 32 * 6 * 13 = 2496
    int sT = bid % 13;
    int rem = bid / 13;
    int cT = rem % 6;
    int b  = rem / 6;
    int c0 = cT * 64, s0 = sT * 64;
    int t = threadIdx.x;
    int ls = t & 63;      // s within tile
    int wv = t >> 6;      // c sub
#pragma unroll
    for (int p = 0; p < 16; ++p) {
        int ci = p * 4 + wv;
        int s = s0 + ls;
        float v = 0.f;
        if (s < 784) v = z[(size_t)(b * 384 + c0 + ci) * 784 + s];
        int cx = ci ^ ((ls & 7) << 3);
        tile[ls * 64 + cx] = f2bf(v);
    }
    __syncthreads();
    int si = t >> 2, sub = t & 3;
    int s = s0 + si;
    if (s >= 784) return;
    int x = si & 7;
    int base0 = ((sub ^ (x >> 1)) << 4) | ((x & 1) << 3);
    int base1 = base0 ^ 8;
    uint4 v0 = *(const uint4*)&tile[si * 64 + base0];
    uint4 v1 = *(const uint4*)&tile[si * 64 + base1];
    size_t ro = (size_t)(b * 784 + s) * 384 + c0 + sub * 16;
    *(uint4*)(zf + ro)     = v0;
    *(uint4*)(zf + ro + 8) = v1;
}

// ---------------- distance GEMM + argmin ----------------
// score(n,k) = ||c_k||^2 - 2 * z_n . c_k ; per-token argmin over all 2048 k.
// A (z tokens) resident in LDS (128x384 bf16, swizzled); B (codebook) streamed
// 256x64 per stage via global_load_lds. 4 waves, each owns 64 rows x 128 cols.
__global__ __launch_bounds__(256, 1) void argmin_kernel(
    const unsigned short* __restrict__ zf, const unsigned short* __restrict__ cb16,
    const float* __restrict__ cnorm, int* __restrict__ midx) {
    __shared__ char smem[BM * D_DIM * 2 + BN * BKS * 2 + K_CB * 4]; // 96K+32K+8K
    char* As = smem;
    char* Bs = smem + BM * D_DIM * 2;
    float* cnl = (float*)(smem + BM * D_DIM * 2 + BN * BKS * 2);

    int t = threadIdx.x;
    int lane = t & 63, wave = t >> 6;
    int r = lane & 15, q = lane >> 4;
    int wrow = (wave >> 1) * 64;    // 0 / 64
    int wcol = (wave & 1) * 128;    // 0 / 128
    int blk = blockIdx.x;           // 196

    for (int i = t; i < K_CB; i += 256) cnl[i] = cnorm[i];

    { // stage A once, pre-swizzled source so linear LDS dest carries swizzle
        const char* srcA = (const char*)(zf + (size_t)blk * BM * D_DIM);
#pragma unroll
        for (int it = 0; it < 24; ++it) {
            uint32_t o   = it * 4096u + (uint32_t)t * 16u;
            uint32_t row = o / 768u;
            uint32_t bo  = o - row * 768u;
            uint32_t so  = row * 768u + (bo ^ ((row & 7u) << 4));
            gl_lds16(srcA + so, As + o);
        }
    }

    float minv[16];
    int   mini[16];
#pragma unroll
    for (int i = 0; i < 16; ++i) { minv[i] = 3.4e38f; mini[i] = 0; }

    for (int nc = 0; nc < NCHUNK; ++nc) {
        f32x4 acc[4][8];
#pragma unroll
        for (int a = 0; a < 4; ++a)
#pragma unroll
            for (int bb = 0; bb < 8; ++bb) acc[a][bb] = (f32x4){0.f, 0.f, 0.f, 0.f};

        for (int ks = 0; ks < KSTEPS; ++ks) {
            __syncthreads();  // prior reads of Bs done (also drains A stage at first pass)
            {
                const char* srcB = (const char*)cb16 + ((size_t)nc * BN) * 768 + (size_t)ks * 128;
#pragma unroll
                for (int it = 0; it < 8; ++it) {
                    uint32_t o   = it * 4096u + (uint32_t)t * 16u;
                    uint32_t row = o >> 7;
                    uint32_t bo  = o & 127u;
                    uint32_t so  = row * 768u + (bo ^ ((row & 7u) << 4));
                    gl_lds16(srcB + so, Bs + o);
                }
            }
            __syncthreads();  // staged data visible

#pragma unroll
            for (int sub = 0; sub < 2; ++sub) {
                int kb = sub * 32;
                short8 a[4], b[8];
#pragma unroll
                for (int mt = 0; mt < 4; ++mt) {
                    uint32_t row   = (uint32_t)(wrow + mt * 16 + r);
                    uint32_t kbyte = (uint32_t)(ks * BKS + kb) * 2 + (uint32_t)q * 16;
                    a[mt] = *(const short8*)(As + row * 768u + (kbyte ^ ((row & 7u) << 4)));
                }
#pragma unroll
                for (int nt = 0; nt < 8; ++nt) {
                    uint32_t row   = (uint32_t)(wcol + nt * 16 + r);
                    uint32_t kbyte = (uint32_t)kb * 2 + (uint32_t)q * 16;
                    b[nt] = *(const short8*)(Bs + row * 128u + (kbyte ^ ((row & 7u) << 4)));
                }
#pragma unroll
                for (int mt = 0; mt < 4; ++mt)
#pragma unroll
                    for (int nt = 0; nt < 8; ++nt)
                        acc[mt][nt] = __builtin_amdgcn_mfma_f32_16x16x32_bf16(
                            a[mt], b[nt], acc[mt][nt], 0, 0, 0);
            }
        }

        // scoring + running argmin. C/D layout: col = lane&15, row = (lane>>4)*4 + j
#pragma unroll
        for (int nt = 0; nt < 8; ++nt) {
            int coll = wcol + nt * 16 + r;
            float cn = cnl[nc * BN + coll];
            int col = nc * BN + coll;
#pragma unroll
            for (int mt = 0; mt < 4; ++mt) {
#pragma unroll
                for (int j = 0; j < 4; ++j) {
                    float val = cn - 2.f * acc[mt][nt][j];
                    int slot = mt * 4 + j;
                    if (val < minv[slot]) { minv[slot] = val; mini[slot] = col; }
                }
            }
        }
    }

    // final argmin across the 16 lanes (same q group) holding each row
#pragma unroll
    for (int slot = 0; slot < 16; ++slot) {
        float v = minv[slot];
        int idx = mini[slot];
#pragma unroll
        for (int d = 1; d < 16; d <<= 1) {
            float ov = __shfl_xor(v, d);
            int   oi = __shfl_xor(idx, d);
            if (ov < v || (ov == v && oi < idx)) { v = ov; idx = oi; }
        }
        if (r == 0) {
            int mt = slot >> 2, j = slot & 3;
            midx[blk * BM + wrow + mt * 16 + q * 4 + j] = idx;
        }
    }
}

// ---------------- gather + output + loss partials ----------------
__global__ __launch_bounds__(256) void gather_out_kernel(
    const float* __restrict__ z, const float* __restrict__ cb,
    const int* __restrict__ midx, float* __restrict__ out,
    float* __restrict__ partials) {
    int t = threadIdx.x;
    int bid = blockIdx.x;                         // 4704
    uint32_t base = ((uint32_t)bid * 256u + (uint32_t)t) * 8u;
    uint32_t s  = base % 784u;
    uint32_t bc = base / 784u;
    uint32_t c  = bc % 384u;
    uint32_t b  = bc / 384u;
    uint32_t n0 = b * 784u + s;
    int4 i0 = *(const int4*)(midx + n0);
    int4 i1 = *(const int4*)(midx + n0 + 4);
    float4 z0 = *(const float4*)(z + base);
    float4 z1 = *(const float4*)(z + base + 4);
    int   idxs[8] = {i0.x, i0.y, i0.z, i0.w, i1.x, i1.y, i1.z, i1.w};
    float zz[8]   = {z0.x, z0.y, z0.z, z0.w, z1.x, z1.y, z1.z, z1.w};
    float o[8];
    float accl = 0.f;
#pragma unroll
    for (int j = 0; j < 8; ++j) {
        float qv = cb[(size_t)idxs[j] * 384 + c];
        o[j] = qv;
        float d = qv - zz[j];
        accl += d * d;
    }
    float4 o0 = {o[0], o[1], o[2], o[3]};
    float4 o1 = {o[4], o[5], o[6], o[7]};
    *(float4*)(out + base)     = o0;
    *(float4*)(out + base + 4) = o1;
#pragma unroll
    for (int d = 32; d; d >>= 1) accl += __shfl_xor(accl, d);
    __shared__ float red[4];
    if ((t & 63) == 0) red[t >> 6] = accl;
    __syncthreads();
    if (t == 0) partials[bid] = (red[0] + red[1]) + (red[2] + red[3]);
}

__global__ __launch_bounds__(256) void finalize_kernel(
    const float* __restrict__ partials, float* __restrict__ out) {
    int t = threadIdx.x;
    float s = 0.f;
    for (int i = t; i < 4704; i += 256) s += partials[i];
#pragma unroll
    for (int d = 32; d; d >>= 1) s += __shfl_xor(s, d);
    __shared__ float red[4];
    if ((t & 63) == 0) red[t >> 6] = s;
    __syncthreads();
    if (t == 0) out[OUT_ELEMS] = 1.25f * ((red[0] + red[1]) + (red[2] + red[3])) / (float)OUT_ELEMS;
}

extern "C" void kernel_launch(void* const* d_in, const int* in_sizes, int n_in,
                              void* d_out, int out_size, void* d_ws, size_t ws_size,
                              hipStream_t stream) {
    const float* z  = (const float*)d_in[0];   // 9,633,792
    const float* cb = (const float*)d_in[1];   // 786,432
    float* out = (float*)d_out;                // 9,633,793
    char* ws = (char*)d_ws;

    // zf (token-major bf16 z, 19.3 MB) lives in d_out's low bytes: it is fully
    // consumed by argmin_kernel before gather_out_kernel overwrites d_out.
    unsigned short* zf = (unsigned short*)d_out;
    unsigned short* cb16 = (unsigned short*)ws;               // 1,572,864 B
    float* cnorm    = (float*)(ws + 1572864);                 //     8,192 B
    int*   midx     = (int*)(ws + 1572864 + 8192);            //   100,352 B
    float* partials = (float*)(ws + 1572864 + 8192 + 100352); //    18,816 B

    prep_cb_kernel<<<512, 256, 0, stream>>>(cb, cb16, cnorm);
    transpose_z_kernel<<<2496, 256, 0, stream>>>(z, zf);
    argmin_kernel<<<196, 256, 0, stream>>>(zf, cb16, cnorm, midx);
    gather_out_kernel<<<4704, 256, 0, stream>>>(z, cb, midx, out, partials);
    finalize_kernel<<<1, 256, 0, stream>>>(partials, out);
}

// Round 2
// 113.682 us; speedup vs baseline: 1.3226x; 1.3226x over previous
//
#include <hip/hip_runtime.h>
#include <stdint.h>

// z (32,384,28,28) fp32; codebook (2048,384) fp32.
// N tokens = 25088, D = 384, K = 2048. out = z_q (9633792 f32) + loss (1 f32).
#define M_TOK 25088
#define D_DIM 384
#define K_CB  2048
#define OUT_ELEMS 9633792
#define MT_TILES 196     // M/128
#define NC_CHUNKS 16     // K_CB/128

typedef __attribute__((ext_vector_type(8))) short short8;
typedef __attribute__((ext_vector_type(4))) float f32x4;

static __device__ __forceinline__ unsigned short f2bf(float f) {
    uint32_t u = __float_as_uint(f);
    u += 0x7FFF + ((u >> 16) & 1);   // RNE
    return (unsigned short)(u >> 16);
}
static __device__ __forceinline__ float bf2f(unsigned short h) {
    return __uint_as_float(((uint32_t)h) << 16);
}
static __device__ __forceinline__ void gl_lds16(const void* g, void* l) {
    __builtin_amdgcn_global_load_lds((const __attribute__((address_space(1))) void*)g,
                                     (__attribute__((address_space(3))) void*)l,
                                     16, 0, 0);
}

// ---------------- codebook prep: fp32 -> bf16 + row norms ----------------
__global__ __launch_bounds__(256) void prep_cb_kernel(
    const float* __restrict__ cb, unsigned short* __restrict__ cb16,
    float* __restrict__ cnorm) {
    int t = threadIdx.x;
    int lane = t & 63, wv = t >> 6;
    int row = blockIdx.x * 4 + wv;               // grid 512 -> 2048 rows
    const float* src = cb + (size_t)row * D_DIM;
    unsigned short* dst = cb16 + (size_t)row * D_DIM;
    float ss = 0.f;
#pragma unroll
    for (int i = 0; i < 6; ++i) {
        float v = src[lane + i * 64];
        dst[lane + i * 64] = f2bf(v);
        ss += v * v;
    }
#pragma unroll
    for (int d = 32; d; d >>= 1) ss += __shfl_xor(ss, d);
    if (lane == 0) cnorm[row] = ss;
}

// ---------------- z transpose + per-token ||z||^2 partials ----------------
// (b,c,s) fp32 -> (token, c) bf16 through 64x64 LDS tiles (XOR swizzle),
// plus znp[cT][token] = sum over this block's 64 c's of z^2 (fp32).
__global__ __launch_bounds__(256) void transpose_z_kernel(
    const float* __restrict__ z, unsigned short* __restrict__ zf,
    float* __restrict__ znp) {
    __shared__ unsigned short tile[64 * 64];
    __shared__ float zred[4][64];
    int bid = blockIdx.x;                 // 32 * 6 * 13 = 2496
    int sT = bid % 13;
    int rem = bid / 13;
    int cT = rem % 6;
    int b  = rem / 6;
    int c0 = cT * 64, s0 = sT * 64;
    int t = threadIdx.x;
    int ls = t & 63;      // s within tile
    int wv = t >> 6;      // c sub
    float ss = 0.f;
#pragma unroll
    for (int p = 0; p < 16; ++p) {
        int ci = p * 4 + wv;
        int s = s0 + ls;
        float v = 0.f;
        if (s < 784) v = z[(size_t)(b * 384 + c0 + ci) * 784 + s];
        ss += v * v;
        int cx = ci ^ ((ls & 7) << 3);
        tile[ls * 64 + cx] = f2bf(v);
    }
    zred[wv][ls] = ss;
    __syncthreads();
    if (t < 64) {
        int s = s0 + t;
        if (s < 784)
            znp[cT * M_TOK + b * 784 + s] =
                (zred[0][t] + zred[1][t]) + (zred[2][t] + zred[3][t]);
    }
    int si = t >> 2, sub = t & 3;
    int s = s0 + si;
    if (s >= 784) return;
    int x = si & 7;
    int base0 = ((sub ^ (x >> 1)) << 4) | ((x & 1) << 3);
    int base1 = base0 ^ 8;
    uint4 v0 = *(const uint4*)&tile[si * 64 + base0];
    uint4 v1 = *(const uint4*)&tile[si * 64 + base1];
    size_t ro = (size_t)(b * 784 + s) * 384 + c0 + sub * 16;
    *(uint4*)(zf + ro)     = v0;
    *(uint4*)(zf + ro + 8) = v1;
}

// ---------------- distance GEMM + partial argmin (m97 structure) ----------------
// grid 3136 = 196 M-tiles x 16 N-chunks. 128x128 tile, BK=64, 4 waves (2x2),
// single-buffered LDS, 2 barriers per K-step, global_load_lds w=16, XOR swizzle.
__global__ __launch_bounds__(256, 3) void argmin2_kernel(
    const unsigned short* __restrict__ zf, const unsigned short* __restrict__ cb16,
    const float* __restrict__ cnorm, float2* __restrict__ partial) {
    __shared__ char As[128 * 128];   // 16 KB: 128 rows x 128 B (one K-step)
    __shared__ char Bs[128 * 128];
    __shared__ float2 comb[2][128];

    int t = threadIdx.x;
    int lane = t & 63, wave = t >> 6;
    int r = lane & 15, q = lane >> 4;
    int wm = wave >> 1, wn = wave & 1;

    // bijective XCD swizzle (nwg=3136, 3136%8==0, q=392): blocks sharing an
    // A-tile (16 consecutive lids) land on one XCD's L2.
    int raw = blockIdx.x;
    int lid = (raw & 7) * 392 + (raw >> 3);
    int mtile = lid >> 4;
    int nc = lid & 15;

    float cnr[4];
#pragma unroll
    for (int nt = 0; nt < 4; ++nt)
        cnr[nt] = cnorm[nc * 128 + wn * 64 + nt * 16 + r];

    const char* abase = (const char*)zf + (size_t)mtile * (128 * 768);
    const char* bbase = (const char*)cb16 + (size_t)nc * (128 * 768);

    f32x4 acc[4][4];
#pragma unroll
    for (int i = 0; i < 4; ++i)
#pragma unroll
        for (int j = 0; j < 4; ++j) acc[i][j] = (f32x4){0.f, 0.f, 0.f, 0.f};

    for (int ks = 0; ks < 6; ++ks) {
        if (ks) __syncthreads();              // prior reads of As/Bs done
        const char* aks = abase + ks * 128;
        const char* bks = bbase + ks * 128;
#pragma unroll
        for (int it = 0; it < 4; ++it) {
            uint32_t o   = it * 4096u + (uint32_t)t * 16u;
            uint32_t row = o >> 7, bo = o & 127u;
            uint32_t so  = row * 768u + (bo ^ ((row & 7u) << 4));
            gl_lds16(aks + so, As + o);
        }
#pragma unroll
        for (int it = 0; it < 4; ++it) {
            uint32_t o   = it * 4096u + (uint32_t)t * 16u;
            uint32_t row = o >> 7, bo = o & 127u;
            uint32_t so  = row * 768u + (bo ^ ((row & 7u) << 4));
            gl_lds16(bks + so, Bs + o);
        }
        __syncthreads();                      // staged data visible

#pragma unroll
        for (int sub = 0; sub < 2; ++sub) {
            uint32_t kb = sub * 64u + (uint32_t)q * 16u;
            short8 a[4], b[4];
#pragma unroll
            for (int mt = 0; mt < 4; ++mt) {
                uint32_t row = (uint32_t)(wm * 64 + mt * 16 + r);
                a[mt] = *(const short8*)(As + row * 128u + (kb ^ ((row & 7u) << 4)));
            }
#pragma unroll
            for (int nt = 0; nt < 4; ++nt) {
                uint32_t row = (uint32_t)(wn * 64 + nt * 16 + r);
                b[nt] = *(const short8*)(Bs + row * 128u + (kb ^ ((row & 7u) << 4)));
            }
#pragma unroll
            for (int mt = 0; mt < 4; ++mt)
#pragma unroll
                for (int nt = 0; nt < 4; ++nt)
                    acc[mt][nt] = __builtin_amdgcn_mfma_f32_16x16x32_bf16(
                        a[mt], b[nt], acc[mt][nt], 0, 0, 0);
        }
    }

    // score + argmin over this block's 128 cols.
    // C/D layout: col = lane&15 (r), row = q*4 + j.
    float minv[16];
    int   mini[16];
#pragma unroll
    for (int i = 0; i < 16; ++i) { minv[i] = 3.4e38f; mini[i] = 0; }
#pragma unroll
    for (int nt = 0; nt < 4; ++nt) {
        int col = nc * 128 + wn * 64 + nt * 16 + r;
        float cn = cnr[nt];
#pragma unroll
        for (int mt = 0; mt < 4; ++mt)
#pragma unroll
            for (int j = 0; j < 4; ++j) {
                float val = cn - 2.f * acc[mt][nt][j];
                int slot = mt * 4 + j;
                if (val < minv[slot]) { minv[slot] = val; mini[slot] = col; }
            }
    }
#pragma unroll
    for (int slot = 0; slot < 16; ++slot) {
        float v = minv[slot];
        int idx = mini[slot];
#pragma unroll
        for (int d = 1; d < 16; d <<= 1) {
            float ov = __shfl_xor(v, d);
            int   oi = __shfl_xor(idx, d);
            if (ov < v || (ov == v && oi < idx)) { v = ov; idx = oi; }
        }
        if (r == 0) {
            int mt = slot >> 2, j = slot & 3;
            float2 e; e.x = v; e.y = __int_as_float(idx);
            comb[wn][wm * 64 + mt * 16 + q * 4 + j] = e;
        }
    }
    __syncthreads();
    if (t < 128) {
        float2 c0 = comb[0][t], c1 = comb[1][t];
        float2 res = (c1.x < c0.x) ? c1 : c0;   // tie -> wn=0 (lower col)
        partial[(size_t)nc * M_TOK + mtile * 128 + t] = res;
    }
}

// ---------------- combine: final argmin + per-token loss ----------------
__global__ __launch_bounds__(256) void combine_kernel(
    const float2* __restrict__ partial, const float* __restrict__ znp,
    int* __restrict__ midx, float* __restrict__ lpart) {
    int t = threadIdx.x;
    int n = blockIdx.x * 256 + t;        // 98 * 256 = 25088
    float2 best = partial[n];
    int bidx = __float_as_int(best.y);
#pragma unroll
    for (int ch = 1; ch < NC_CHUNKS; ++ch) {
        float2 p = partial[(size_t)ch * M_TOK + n];
        int pi = __float_as_int(p.y);
        if (p.x < best.x || (p.x == best.x && pi < bidx)) { best = p; bidx = pi; }
    }
    midx[n] = bidx;
    float zn = 0.f;
#pragma unroll
    for (int cT = 0; cT < 6; ++cT) zn += znp[cT * M_TOK + n];
    float lt = best.x + zn;              // ~ ||z_n - c_idx||^2
#pragma unroll
    for (int d = 32; d; d >>= 1) lt += __shfl_xor(lt, d);
    __shared__ float red[4];
    if ((t & 63) == 0) red[t >> 6] = lt;
    __syncthreads();
    if (t == 0) lpart[blockIdx.x] = (red[0] + red[1]) + (red[2] + red[3]);
}

// ---------------- output broadcast: out[(b,c,s)] = cb[midx[b,s]][c] ----------------
// Block = 56 tokens x all 384 c. Gather cb rows coalesced -> LDS (bf16, padded
// stride 392), then write out coalesced along s.
__global__ __launch_bounds__(256) void gather_out_kernel(
    const float* __restrict__ cb, const int* __restrict__ midx,
    float* __restrict__ out) {
    __shared__ unsigned short tile[56 * 392];
    __shared__ int lidx[56];
    int t = threadIdx.x;
    int bid = blockIdx.x;                 // 448 = 32 b * 14 sT
    int b = bid / 14, sT = bid % 14;
    int n0 = b * 784 + sT * 56;
    if (t < 56) lidx[t] = midx[n0 + t];
    __syncthreads();
#pragma unroll
    for (int p = 0; p < 21; ++p) {
        int e = (p * 256 + t) * 4;        // 21504 elems = 21*256*4
        int tok = e / 384;
        int c = e - tok * 384;
        int idx = lidx[tok];
        float4 v = *(const float4*)(cb + (size_t)idx * 384 + c);
        uint2 u;
        u.x = (uint32_t)f2bf(v.x) | ((uint32_t)f2bf(v.y) << 16);
        u.y = (uint32_t)f2bf(v.z) | ((uint32_t)f2bf(v.w) << 16);
        *(uint2*)&tile[tok * 392 + c] = u;
    }
    __syncthreads();
#pragma unroll
    for (int p = 0; p < 42; ++p) {
        int pp = p * 256 + t;             // 10752 float2 = 42*256
        int c = pp / 28;
        int j = (pp - c * 28) * 2;
        float f0 = bf2f(tile[j * 392 + c]);
        float f1 = bf2f(tile[(j + 1) * 392 + c]);
        size_t off = ((size_t)b * 384 + c) * 784 + (size_t)sT * 56 + j;
        float2 o; o.x = f0; o.y = f1;
        *(float2*)(out + off) = o;
    }
}

__global__ __launch_bounds__(256) void finalize_kernel(
    const float* __restrict__ lpart, float* __restrict__ out) {
    int t = threadIdx.x;
    float s = 0.f;
    for (int i = t; i < 98; i += 256) s += lpart[i];
#pragma unroll
    for (int d = 32; d; d >>= 1) s += __shfl_xor(s, d);
    __shared__ float red[4];
    if ((t & 63) == 0) red[t >> 6] = s;
    __syncthreads();
    if (t == 0) out[OUT_ELEMS] = 1.25f * ((red[0] + red[1]) + (red[2] + red[3])) / (float)OUT_ELEMS;
}

extern "C" void kernel_launch(void* const* d_in, const int* in_sizes, int n_in,
                              void* d_out, int out_size, void* d_ws, size_t ws_size,
                              hipStream_t stream) {
    const float* z  = (const float*)d_in[0];
    const float* cb = (const float*)d_in[1];
    float* out = (float*)d_out;
    char* ws = (char*)d_ws;

    // zf (token-major bf16 z, 19.3 MB) borrows d_out: fully consumed by
    // argmin2_kernel before gather_out_kernel overwrites d_out.
    unsigned short* zf = (unsigned short*)d_out;

    unsigned short* cb16 = (unsigned short*)ws;            // 1,572,864 B
    float*  cnorm   = (float*)(ws + 1572864);              //     8,192 B
    int*    midx    = (int*)(ws + 1581056);                //   100,352 B
    float*  znp     = (float*)(ws + 1681408);              //   602,112 B
    float2* partial = (float2*)(ws + 2283520);             // 3,211,264 B
    float*  lpart   = (float*)(ws + 5494784);              //       392 B

    prep_cb_kernel<<<512, 256, 0, stream>>>(cb, cb16, cnorm);
    transpose_z_kernel<<<2496, 256, 0, stream>>>(z, zf, znp);
    argmin2_kernel<<<3136, 256, 0, stream>>>(zf, cb16, cnorm, partial);
    combine_kernel<<<98, 256, 0, stream>>>(partial, znp, midx, lpart);
    gather_out_kernel<<<448, 256, 0, stream>>>(cb, midx, out);
    finalize_kernel<<<1, 256, 0, stream>>>(lpart, out);
}